// Round 8
// baseline (5762.376 us; speedup 1.0000x reference)
//
#include <hip/hip_runtime.h>
#include <math.h>

typedef _Float16 f16;
typedef _Float16 half8 __attribute__((ext_vector_type(8)));
typedef _Float16 half4v __attribute__((ext_vector_type(4)));
typedef float f32x4 __attribute__((ext_vector_type(4)));

#define BATCH 8192
#define SDIM  1024
#define HDIM  2048
#define DECD  1024
#define EMBD  256
#define G3    3072
#define VOCAB 169
#define VPADX 192
#define NFRAG 11
#define TLEN  20
#define SOS_TOK 166
#define IGN_TOK 168
#define OUTC  166
#define NGRU_BLK 2048
#define NLOG_BLK 512

#define GLOAD16(gp, lp) __builtin_amdgcn_global_load_lds( \
    (const __attribute__((address_space(1))) unsigned int*)(gp), \
    (__attribute__((address_space(3))) unsigned int*)(lp), 16, 0, 0)

// fp16x2 split: a ~= hi + lo/2048, avoids fp16-subnormal hi for tiny a
__device__ __forceinline__ void split2(float a, f16& h, f16& l)
{
    float hi = (fabsf(a) >= 6.103515625e-05f) ? (float)(f16)a : 0.0f;
    h = (f16)hi;
    l = (f16)((a - hi) * 2048.0f);
}

__device__ __forceinline__ float join2(f16 h, f16 l)
{
    return (float)h + (float)l * 4.8828125e-4f;
}

// LDS tile swizzle: rows paired into 128B lines, 16B slots XORed by line&7
__device__ __forceinline__ int swz(int r, int k0)   // halfword offset
{
    const int line = r >> 1;
    const int s = (((r & 1) << 2) | (k0 >> 3)) ^ (line & 7);
    return line * 64 + s * 8;
}

// ============ fp16x2 3-pass MFMA GEMM: C = op(A[M,K] @ Bt[N,K]^T + bias) ============
// MODE bit0: write fp32 C; bit1: write split (Ch, Cl)
template<int MODE>
__global__ __launch_bounds__(256, 2)
void gemm16(const f16* __restrict__ Ah, const f16* __restrict__ Al,
            const f16* __restrict__ Bh, const f16* __restrict__ Bl,
            const float* __restrict__ bias, float* __restrict__ C,
            f16* __restrict__ Ch, f16* __restrict__ Cl,
            int M, int N, int K, int relu)
{
    __shared__ __align__(16) f16 lds[4][4096];   // Ahi, Alo, Bhi, Blo (8KB each)

    const int nx = N >> 7;
    const int cpx = gridDim.x >> 3;              // grids are %8==0
    int wg = blockIdx.x;
    wg = (wg & 7) * cpx + (wg >> 3);             // XCD-aware swizzle
    const int m0 = (wg / nx) << 7;
    const int n0 = (wg % nx) << 7;

    const int tid = threadIdx.x;
    const int w = tid >> 6;
    const int lane = tid & 63;
    const int wr = w >> 1, wc = w & 1;

    const int qq = (lane & 7) ^ (lane >> 3);
    const int row_off = ((lane >> 3) << 1) | (qq >> 2);
    const int k_off = (qq & 3) << 3;
    const f16* sb = (w == 0) ? Ah + (size_t)m0 * K
                  : (w == 1) ? Al + (size_t)m0 * K
                  : (w == 2) ? Bh + (size_t)n0 * K
                             : Bl + (size_t)n0 * K;
    sb += (size_t)row_off * K + k_off;
    f16* lb = &lds[w][0];

    int offA[4], offB[4];
    {
        const int fr = lane & 15, k0 = (lane >> 4) << 3;
#pragma unroll
        for (int t = 0; t < 4; ++t) {
            offA[t] = swz(wr * 64 + t * 16 + fr, k0);
            offB[t] = swz(wc * 64 + t * 16 + fr, k0);
        }
    }

    f32x4 acch[4][4], accl[4][4];
#pragma unroll
    for (int i = 0; i < 4; ++i)
#pragma unroll
        for (int j = 0; j < 4; ++j) { acch[i][j] = (f32x4)0.0f; accl[i][j] = (f32x4)0.0f; }

    const int nkt = K >> 5;
    const size_t K16 = (size_t)K * 16;
    for (int kt = 0; kt < nkt; ++kt) {
        const f16* s = sb + kt * 32;
#pragma unroll
        for (int i = 0; i < 8; ++i)
            GLOAD16(s + (size_t)i * K16, lb + i * 512);
        __syncthreads();

        half8 fah[4], fbh[4], fal[4], fbl[4];
#pragma unroll
        for (int t = 0; t < 4; ++t) {
            fah[t] = *(const half8*)&lds[0][offA[t]];
            fal[t] = *(const half8*)&lds[1][offA[t]];
            fbh[t] = *(const half8*)&lds[2][offB[t]];
            fbl[t] = *(const half8*)&lds[3][offB[t]];
        }
#pragma unroll
        for (int i = 0; i < 4; ++i)
#pragma unroll
            for (int j = 0; j < 4; ++j) {
                acch[i][j] = __builtin_amdgcn_mfma_f32_16x16x32_f16(fah[i], fbh[j], acch[i][j], 0, 0, 0);
                accl[i][j] = __builtin_amdgcn_mfma_f32_16x16x32_f16(fal[i], fbh[j], accl[i][j], 0, 0, 0);
                accl[i][j] = __builtin_amdgcn_mfma_f32_16x16x32_f16(fah[i], fbl[j], accl[i][j], 0, 0, 0);
            }
        __syncthreads();
    }

    const float inv2048 = 4.8828125e-4f;
    const int fr = lane & 15;
    const int fq = lane >> 4;
#pragma unroll
    for (int j = 0; j < 4; ++j) {
        const int col = n0 + wc * 64 + j * 16 + fr;
        const float bc = bias[col];
#pragma unroll
        for (int i = 0; i < 4; ++i) {
            const int row0 = m0 + wr * 64 + i * 16 + fq * 4;
            const f32x4 vh = acch[i][j], vl = accl[i][j];
#pragma unroll
            for (int r = 0; r < 4; ++r) {
                float v = vh[r] + vl[r] * inv2048 + bc;
                if (relu) v = fmaxf(v, 0.0f);
                const size_t o = (size_t)(row0 + r) * N + col;
                if constexpr (MODE & 1) C[o] = v;
                if constexpr (MODE & 2) { f16 hh, hl; split2(v, hh, hl); Ch[o] = hh; Cl[o] = hl; }
            }
        }
    }
}

// ============ merged decoder step: [blocks < ngru] fused GRU GEMM+gates,
//              [blocks >= ngru] logits+argmax+CE for the PREVIOUS step (reads same h input).
#define STAGE_V2(KT) do {                                                          \
    const int ko_ = (KT) * 32 + k_off;                                             \
    if (w == 0) {                                                                  \
        const f16* sp = hch + (size_t)(m0 + row_off) * DECD + ko_;                 \
        _Pragma("unroll") for (int i_ = 0; i_ < 8; ++i_)                           \
            GLOAD16(sp + (size_t)i_ * (16 * DECD), &lds[i_ * 512]);                \
    } else if (w == 1) {                                                           \
        const f16* sp = hcl + (size_t)(m0 + row_off) * DECD + ko_;                 \
        _Pragma("unroll") for (int i_ = 0; i_ < 8; ++i_)                           \
            GLOAD16(sp + (size_t)i_ * (16 * DECD), &lds[4096 + i_ * 512]);         \
    } else if (w == 2) {                                                           \
        _Pragma("unroll") for (int g_ = 0; g_ < 3; ++g_) {                         \
            const f16* sp = whh + (size_t)(g_ * DECD + n0 + row_off) * DECD + ko_; \
            _Pragma("unroll") for (int i_ = 0; i_ < 2; ++i_)                       \
                GLOAD16(sp + (size_t)i_ * (16 * DECD),                             \
                        &lds[8192 + g_ * 1024 + i_ * 512]);                        \
        }                                                                          \
    } else {                                                                       \
        _Pragma("unroll") for (int g_ = 0; g_ < 3; ++g_) {                         \
            const f16* sp = whl + (size_t)(g_ * DECD + n0 + row_off) * DECD + ko_; \
            _Pragma("unroll") for (int i_ = 0; i_ < 2; ++i_)                       \
                GLOAD16(sp + (size_t)i_ * (16 * DECD),                             \
                        &lds[11264 + g_ * 1024 + i_ * 512]);                       \
        }                                                                          \
    }                                                                              \
} while (0)

__global__ __launch_bounds__(256, 3)
void step_fused(const f16* __restrict__ hch, const f16* __restrict__ hcl,
                const f16* __restrict__ whh, const f16* __restrict__ whl,
                const float* __restrict__ bhh, const float* __restrict__ gx0,
                const float* __restrict__ tg, const int* __restrict__ tseq,
                int t, f16* __restrict__ hnh, f16* __restrict__ hnl,
                const f16* __restrict__ wph, const f16* __restrict__ wpl,
                const float* __restrict__ bp, int tlog,
                float* __restrict__ pred, float* __restrict__ accb,
                int ngru)
{
    __shared__ __align__(16) f16 lds[14336];      // 28KB (gru staging / logits reduce)

    if ((int)blockIdx.x < ngru) {
        // ================= GRU path (round-7 gru_fused, unchanged) =================
        const int chunk = blockIdx.x & 7;             // -> XCD (HW round-robin)
        const int q     = blockIdx.x >> 3;            // 0..255, row-major within chunk
        const int m0 = (q >> 2) << 7;                 // 64 row-tiles of 128
        const int n0 = (chunk * 4 + (q & 3)) << 5;    // 4 col-strips of 32 per XCD

        const int tid = threadIdx.x, w = tid >> 6, lane = tid & 63;
        const int wr = w >> 1, wc = w & 1;

        const int qq = (lane & 7) ^ (lane >> 3);
        const int row_off = ((lane >> 3) << 1) | (qq >> 2);
        const int k_off = (qq & 3) << 3;

        const int fr = lane & 15, kq8 = (lane >> 4) << 3;
        int offA[4];
#pragma unroll
        for (int i = 0; i < 4; ++i) offA[i] = swz(wr * 64 + i * 16 + fr, kq8);
        const int offB = swz(wc * 16 + fr, kq8);

        f32x4 aH[3][4], aL[3][4];
#pragma unroll
        for (int g = 0; g < 3; ++g)
#pragma unroll
            for (int i = 0; i < 4; ++i) { aH[g][i] = (f32x4)0.0f; aL[g][i] = (f32x4)0.0f; }

        for (int kt = 0; kt < DECD / 32; ++kt) {
            STAGE_V2(kt);
            __syncthreads();

            half8 fah[4], fal[4];
#pragma unroll
            for (int i = 0; i < 4; ++i) {
                fah[i] = *(const half8*)&lds[offA[i]];
                fal[i] = *(const half8*)&lds[4096 + offA[i]];
            }
#pragma unroll
            for (int g = 0; g < 3; ++g) {
                const half8 bh = *(const half8*)&lds[8192 + g * 1024 + offB];
                const half8 bl = *(const half8*)&lds[11264 + g * 1024 + offB];
#pragma unroll
                for (int i = 0; i < 4; ++i) {
                    aH[g][i] = __builtin_amdgcn_mfma_f32_16x16x32_f16(fah[i], bh, aH[g][i], 0, 0, 0);
                    aL[g][i] = __builtin_amdgcn_mfma_f32_16x16x32_f16(fal[i], bh, aL[g][i], 0, 0, 0);
                    aL[g][i] = __builtin_amdgcn_mfma_f32_16x16x32_f16(fah[i], bl, aL[g][i], 0, 0, 0);
                }
            }
            __syncthreads();
        }

        const float inv = 4.8828125e-4f;
        const int fq = lane >> 4;
        const int col = n0 + wc * 16 + fr;
        const float br = bhh[col];
        const float bz = bhh[DECD + col];
        const float bn = bhh[2 * DECD + col];
#pragma unroll
        for (int i = 0; i < 4; ++i) {
#pragma unroll
            for (int r = 0; r < 4; ++r) {
                const int row = m0 + wr * 64 + i * 16 + fq * 4 + r;
                const int tok = (t == 0) ? SOS_TOK : tseq[(size_t)row * TLEN + (t - 1)];
                const size_t gb = (size_t)row * G3;
                const size_t tb = (size_t)tok * G3;
                const float ghr = aH[0][i][r] + aL[0][i][r] * inv + br;
                const float ghz = aH[1][i][r] + aL[1][i][r] * inv + bz;
                const float ghn = aH[2][i][r] + aL[2][i][r] * inv + bn;
                const float gir = gx0[gb + col] + tg[tb + col];
                const float giz = gx0[gb + DECD + col] + tg[tb + DECD + col];
                const float gin = gx0[gb + 2 * DECD + col] + tg[tb + 2 * DECD + col];
                const float rr = 1.f / (1.f + expf(-(gir + ghr)));
                const float zz = 1.f / (1.f + expf(-(giz + ghz)));
                const float nn = tanhf(gin + rr * ghn);
                const size_t hidx = (size_t)row * DECD + col;
                const float hp = join2(hch[hidx], hcl[hidx]);
                const float hv = (1.f - zz) * nn + zz * hp;
                f16 a_, b_; split2(hv, a_, b_);
                hnh[hidx] = a_;
                hnl[hidx] = b_;
            }
        }
    } else {
        // ================= logits path (step tlog, input h = hch/hcl) =================
        // wave wv owns frags fb0..fb0+2 (fb0 = 3*wv); full K per wave; cross-wave LDS combine.
        float* red = (float*)&lds[0];                 // [4][16][4] floats = 1 KB
        const int tid = threadIdx.x, wv = tid >> 6, lane = tid & 63;
        const int lb = blockIdx.x - ngru;
        const int b0 = lb << 4;
        const int fr = lane & 15, kq = lane >> 4;
        const int fb0 = wv * 3;

        const f16* pa_h = hch + (size_t)(b0 + fr) * DECD + kq * 8;
        const f16* pa_l = hcl + (size_t)(b0 + fr) * DECD + kq * 8;
        const f16* pb_h = wph + (size_t)(fb0 * 16 + fr) * DECD + kq * 8;
        const f16* pb_l = wpl + (size_t)(fb0 * 16 + fr) * DECD + kq * 8;

        f32x4 acch[3], accl[3];
#pragma unroll
        for (int f = 0; f < 3; ++f) { acch[f] = (f32x4)0.0f; accl[f] = (f32x4)0.0f; }

#pragma unroll 2
        for (int kt = 0; kt < 32; ++kt) {
            const int ko = kt * 32;
            const half8 a_h = *(const half8*)(pa_h + ko);
            const half8 a_l = *(const half8*)(pa_l + ko);
#pragma unroll
            for (int f = 0; f < 3; ++f) {
                const half8 b_h = *(const half8*)(pb_h + (size_t)f * 16 * DECD + ko);
                const half8 b_l = *(const half8*)(pb_l + (size_t)f * 16 * DECD + ko);
                acch[f] = __builtin_amdgcn_mfma_f32_16x16x32_f16(a_h, b_h, acch[f], 0, 0, 0);
                accl[f] = __builtin_amdgcn_mfma_f32_16x16x32_f16(a_l, b_h, accl[f], 0, 0, 0);
                accl[f] = __builtin_amdgcn_mfma_f32_16x16x32_f16(a_h, b_l, accl[f], 0, 0, 0);
            }
        }

        const float inv = 4.8828125e-4f;
#pragma unroll
        for (int r = 0; r < 4; ++r) {
            float vv[3];
            float m = -3.0e38f; int mi = 0;
#pragma unroll
            for (int f = 0; f < 3; ++f) {
                const int col = (fb0 + f) * 16 + fr;
                const float bb = (col < VOCAB) ? bp[col] : -1.0e30f;
                vv[f] = acch[f][r] + accl[f][r] * inv + bb;
                if (vv[f] > m) { m = vv[f]; mi = col; }
            }
#pragma unroll
            for (int off = 8; off >= 1; off >>= 1) {
                const float om = __shfl_xor(m, off);
                const int   oi = __shfl_xor(mi, off);
                if (om > m || (om == m && oi < mi)) { m = om; mi = oi; }
            }
            const int b = b0 + kq * 4 + r;
            const int tgt = tseq[(size_t)b * TLEN + tlog];
            float se = 0.f, tl = 0.f;
#pragma unroll
            for (int f = 0; f < 3; ++f) {
                se += expf(vv[f] - m);
                const int col = (fb0 + f) * 16 + fr;
                if (col == tgt) tl = vv[f];
            }
#pragma unroll
            for (int off = 8; off >= 1; off >>= 1) {
                se += __shfl_xor(se, off);
                tl += __shfl_xor(tl, off);
            }
            if (fr == 0) {
                const int row = kq * 4 + r;
                red[(wv * 16 + row) * 4 + 0] = m;
                red[(wv * 16 + row) * 4 + 1] = (float)mi;
                red[(wv * 16 + row) * 4 + 2] = se;
                red[(wv * 16 + row) * 4 + 3] = tl;
            }
        }
        __syncthreads();

        float wnll = 0.f, wcnt = 0.f;
        if (wv == 0 && lane < 16) {
            const int row = lane;
            float M = red[row * 4 + 0];
            int  MI = (int)red[row * 4 + 1];
#pragma unroll
            for (int wq = 1; wq < 4; ++wq) {
                const float mw = red[(wq * 16 + row) * 4 + 0];
                if (mw > M) { M = mw; MI = (int)red[(wq * 16 + row) * 4 + 1]; }
            }
            float se = 0.f, tl = 0.f;
#pragma unroll
            for (int wq = 0; wq < 4; ++wq) {
                se += red[(wq * 16 + row) * 4 + 2] * expf(red[(wq * 16 + row) * 4 + 0] - M);
                tl += red[(wq * 16 + row) * 4 + 3];
            }
            const int b = b0 + row;
            if (MI < OUTC) pred[(size_t)b * OUTC + MI] = 1.0f;
            const int tgt = tseq[(size_t)b * TLEN + tlog];
            if (tgt != IGN_TOK) { wnll = M + logf(se) - tl; wcnt = 1.f; }
        }
        if (wv == 0) {
#pragma unroll
            for (int off = 32; off >= 1; off >>= 1) {
                wnll += __shfl_xor(wnll, off);
                wcnt += __shfl_xor(wcnt, off);
            }
            if (lane == 0) {
                atomicAdd(&accb[0], wnll);
                atomicAdd(&accb[1], wcnt);
            }
        }
    }
}

// ============ weight transpose + split: W[K][N] -> Wt_hi/lo [N][K] ============
__global__ __launch_bounds__(256)
void transpose_split(const float* __restrict__ Wm, f16* __restrict__ th, f16* __restrict__ tl,
                     int K, int N)
{
    __shared__ float tile[32][33];
    const int n0 = blockIdx.x << 5, k0 = blockIdx.y << 5;
    const int tx = threadIdx.x & 31, ty = threadIdx.x >> 5;
#pragma unroll
    for (int j = 0; j < 32; j += 8)
        tile[ty + j][tx] = Wm[(size_t)(k0 + ty + j) * N + n0 + tx];
    __syncthreads();
#pragma unroll
    for (int j = 0; j < 32; j += 8) {
        const float a = tile[tx][ty + j];
        f16 hh, hl; split2(a, hh, hl);
        const size_t o = (size_t)(n0 + ty + j) * K + k0 + tx;
        th[o] = hh; tl[o] = hl;
    }
}

// ============ Wp transpose+split, padded to 192 rows: Wp[1024][169] -> wph/wpl[192][1024] ============
__global__ __launch_bounds__(256)
void wp_split(const float* __restrict__ Wp, f16* __restrict__ wph, f16* __restrict__ wpl)
{
    const int k = blockIdx.x * 256 + threadIdx.x;
    const int n = blockIdx.y;
    const float a = (n < VOCAB) ? Wp[(size_t)k * VOCAB + n] : 0.0f;
    f16 h, l; split2(a, h, l);
    wph[(size_t)n * DECD + k] = h;
    wpl[(size_t)n * DECD + k] = l;
}

// ============ activation split (s input) ============
__global__ __launch_bounds__(256)
void split_act(const float* __restrict__ x, f16* __restrict__ xh, f16* __restrict__ xl)
{
    const int i = blockIdx.x * 256 + threadIdx.x;
    const float4 v = ((const float4*)x)[i];
    half4v hh, hl;
#pragma unroll
    for (int c = 0; c < 4; ++c) { f16 a, b; split2((&v.x)[c], a, b); hh[c] = a; hl[c] = b; }
    ((half4v*)xh)[i] = hh;
    ((half4v*)xl)[i] = hl;
}

// ---------------- tokgi[v] = emb[v] @ Wih[0:256, :]  ([169, 3072]) ----------------
__global__ __launch_bounds__(256)
void tok_gi(const float* __restrict__ emb, const float* __restrict__ Wih,
            float* __restrict__ tg)
{
    __shared__ float es[EMBD];
    const int v = blockIdx.y;
    const int n = blockIdx.x * 256 + threadIdx.x;
    es[threadIdx.x] = emb[(size_t)v * EMBD + threadIdx.x];
    __syncthreads();
    float s = 0.f;
#pragma unroll 8
    for (int k = 0; k < EMBD; ++k)
        s = fmaf(es[k], Wih[(size_t)k * G3 + n], s);
    tg[(size_t)v * G3 + n] = s;
}

__global__ void finalize_loss(const float* __restrict__ accb, float* __restrict__ out)
{
    out[0] = accb[0] / fmaxf(accb[1], 1.f);
}

extern "C" void kernel_launch(void* const* d_in, const int* in_sizes, int n_in,
                              void* d_out, int out_size, void* d_ws, size_t ws_size,
                              hipStream_t stream)
{
    const float* s    = (const float*)d_in[0];
    const int*   aseq = (const int*)  d_in[1];
    const float* W1   = (const float*)d_in[2];
    const float* b1   = (const float*)d_in[3];
    const float* W2   = (const float*)d_in[4];
    const float* b2   = (const float*)d_in[5];
    const float* emb  = (const float*)d_in[6];
    const float* Wih  = (const float*)d_in[7];
    const float* Whh  = (const float*)d_in[8];
    const float* bih  = (const float*)d_in[9];
    const float* bhh  = (const float*)d_in[10];
    const float* Wp   = (const float*)d_in[11];
    const float* bp   = (const float*)d_in[12];
    float* outp = (float*)d_out;
    char* W = (char*)d_ws;

    // ---- arena (bytes), total ~134 MB ----
    const size_t SZ_H = (size_t)BATCH * DECD * 2;            // 16.78 MB per half
    const size_t o_gx0 = 0;                                  // [8192,3072] f32
    const size_t o_hAh = o_gx0 + (size_t)BATCH * G3 * 4;
    const size_t o_hAl = o_hAh + SZ_H;
    const size_t o_hBh = o_hAl + SZ_H;
    const size_t o_hBl = o_hBh + SZ_H;
    const size_t o_tg  = o_hBl + SZ_H;                       // [169,3072] f32
    const size_t o_whh = o_tg  + (size_t)VOCAB * G3 * 4;
    const size_t o_whl = o_whh + (size_t)DECD * G3 * 2;
    const size_t o_wph = o_whl + (size_t)DECD * G3 * 2;
    const size_t o_wpl = o_wph + (size_t)VPADX * DECD * 2;
    const size_t o_acc = o_wpl + (size_t)VPADX * DECD * 2;
    const size_t need  = o_acc + 256;
    if (ws_size < need) return;

    float* gx0  = (float*)(W + o_gx0);
    f16*   hAh  = (f16*)(W + o_hAh);
    f16*   hAl  = (f16*)(W + o_hAl);
    f16*   hBh  = (f16*)(W + o_hBh);
    f16*   hBl  = (f16*)(W + o_hBl);
    float* tg   = (float*)(W + o_tg);
    f16*   whh  = (f16*)(W + o_whh);
    f16*   whl  = (f16*)(W + o_whl);
    f16*   wph  = (f16*)(W + o_wph);
    f16*   wpl  = (f16*)(W + o_wpl);
    float* accb = (float*)(W + o_acc);

    // setup transients aliased into dead regions:
    f16* h1h = (f16*)(W + o_gx0);                                  // [8192,2048] halves in gx0
    f16* h1l = (f16*)(W + o_gx0 + (size_t)BATCH * HDIM * 2);
    f16* w1h = (f16*)(W + o_gx0 + (size_t)BATCH * HDIM * 4);       // after h1 (67.1 MB)
    f16* w1l = (f16*)(W + o_gx0 + (size_t)BATCH * HDIM * 4 + (size_t)SDIM * HDIM * 2);
    f16* w2h = w1h;                                                // w1 dead after gemm1
    f16* w2l = (f16*)(W + o_gx0 + (size_t)BATCH * HDIM * 4 + (size_t)HDIM * DECD * 2);
    f16* sh  = (f16*)(W + o_hBh);                                  // s split in h-buf B
    f16* sl  = (f16*)(W + o_hBh + (size_t)BATCH * SDIM * 2);
    f16* wih = whh;                                                // Wih^T split in whh slots
    f16* wil = whl;                                                // (overwritten by Whh later)

    hipMemsetAsync(d_out, 0, (size_t)out_size * sizeof(float), stream);
    hipMemsetAsync(accb, 0, 2 * sizeof(float), stream);

    // ---- setup ----
    split_act<<<dim3(BATCH * SDIM / 4 / 256), 256, 0, stream>>>(s, sh, sl);
    transpose_split<<<dim3(HDIM/32, SDIM/32), 256, 0, stream>>>(W1, w1h, w1l, SDIM, HDIM);
    tok_gi<<<dim3(G3/256, VOCAB), 256, 0, stream>>>(emb, Wih, tg);
    wp_split<<<dim3(DECD/256, VPADX), 256, 0, stream>>>(Wp, wph, wpl);

    // h1 = relu(s@W1+b1): split only, into gx0 region
    gemm16<2><<<dim3((BATCH/128)*(HDIM/128)), 256, 0, stream>>>(
        sh, sl, w1h, w1l, b1, nullptr, h1h, h1l, BATCH, HDIM, SDIM, 1);

    transpose_split<<<dim3(DECD/32, HDIM/32), 256, 0, stream>>>(W2, w2h, w2l, HDIM, DECD);
    // h0 = h1@W2+b2: split into h-buf A
    gemm16<2><<<dim3((BATCH/128)*(DECD/128)), 256, 0, stream>>>(
        h1h, h1l, w2h, w2l, b2, nullptr, hAh, hAl, BATCH, DECD, HDIM, 0);

    transpose_split<<<dim3(G3/32, DECD/32), 256, 0, stream>>>(Wih + (size_t)EMBD * G3, wih, wil, DECD, G3);
    // gx0 = h0@Wih[256:]+bih (overwrites dead h1/w2 transients)
    gemm16<1><<<dim3((BATCH/128)*(G3/128)), 256, 0, stream>>>(
        hAh, hAl, wih, wil, bih, gx0, nullptr, nullptr, BATCH, G3, DECD, 0);

    transpose_split<<<dim3(G3/32, DECD/32), 256, 0, stream>>>(Whh, whh, whl, DECD, G3);

    // ---- decoder loop: K_0 = gru(0); K_t = gru(t) || logits(t-1); final logits(19) ----
    f16 *ch = hAh, *cl = hAl, *nh = hBh, *nl = hBl;
    // t = 0: gru only
    step_fused<<<dim3(NGRU_BLK), 256, 0, stream>>>(
        ch, cl, whh, whl, bhh, gx0, tg, aseq, 0, nh, nl,
        wph, wpl, bp, 0, outp + 1, accb, NGRU_BLK);
    { f16* tmp = ch; ch = nh; nh = tmp; tmp = cl; cl = nl; nl = tmp; }

    for (int t = 1; t < TLEN; ++t) {
        step_fused<<<dim3(NGRU_BLK + NLOG_BLK), 256, 0, stream>>>(
            ch, cl, whh, whl, bhh, gx0, tg, aseq, t, nh, nl,
            wph, wpl, bp, t - 1, outp + 1, accb, NGRU_BLK);
        f16* tmp = ch; ch = nh; nh = tmp;
        tmp = cl; cl = nl; nl = tmp;
    }
    // final logits on h^20 (in ch after the last swap)
    step_fused<<<dim3(NLOG_BLK), 256, 0, stream>>>(
        ch, cl, whh, whl, bhh, gx0, tg, aseq, 0, nh, nl,
        wph, wpl, bp, TLEN - 1, outp + 1, accb, 0);

    finalize_loss<<<1, 1, 0, stream>>>(accb, outp);
}